// Round 2
// baseline (410.134 us; speedup 1.0000x reference)
//
#include <hip/hip_runtime.h>

namespace {

constexpr float C2  = 0.2f;   // DT/DX^2 (stencil coefficient)
constexpr float DTC = 0.2f;   // DT
constexpr float IDT = 5.0f;   // 1/DT

// LDS float offset for (row, ycc, h): float4-unit = (ycc + 8h) ^ (row&15).
// Bank-group (= unit mod 8) = ycc ^ (row&7): bijective over the 8 ycc lanes
// for every row and both halves h, so each wave-level b128 read/write of a
// row spans all 8 bank groups. (Round-0's q0=2*ycc even-unit scheme hit only
// 4 of 8 groups -> 4-way conflicts, 12.5M cycles.)
__device__ __forceinline__ int ldsOff(int row, int ycc, int h) {
    return ((row << 4) + ((ycc + (h << 3)) ^ (row & 15))) << 2;   // float offset
}

// 256 blocks = 32 batches x 4 groups x 2 parts. Every block runs a 2-field
// scan (xi + ONE extra field) -- round-1/2 wall was total per-CU work (all
// blocks redundantly ran the full 4-field scan), not occupancy:
//   group 0: extra = f4 (pace-balancing dummy), stores ch0..3 (dw,xi,I1,I2)
//   group 1: extra = f4, stores ch4
//   group 2: extra = f5, stores ch5
//   group 3: extra = f6, stores ch6
// part p stores x-rows [32p, 32p+32). Total field-scans/batch: 32 -> 16.
// blockIdx = (group*2+part)*32 + b keeps all 8 blocks of a batch on XCD b%8:
// W fetched once per XCD L2 (round-1: FETCH 131->16 MB) and the split-channel
// stores to the same 28B output cells merge in one XCD's L2.
__global__ __launch_bounds__(512, 2)
void fused_scan(const float* __restrict__ W, float* __restrict__ out) {
    // double-buffered scan state: one barrier per iteration.
    __shared__ float sxi[2][4096];
    __shared__ float sex[2][4096];

    const int tid   = threadIdx.x;
    const int b     = blockIdx.x & 31;
    const int gi    = blockIdx.x >> 5;   // 0..7
    const int group = gi >> 1;           // 0..3
    const int part  = gi & 1;            // 0..1

    const int x   = tid >> 3;      // row 0..63
    const int ycc = tid & 7;       // y-chunk 0..7 (8 consecutive y each)
    const int yo  = ycc << 3;      // first y of this thread

    const bool mine = ((x >> 5) == part);   // wave-uniform store guard (4 waves)

    // wave = 8 consecutive rows x 8 y-chunks; y+-1 neighbors are in-wave
    const int lane   = tid & 63;
    const int laneYm = (lane & 56) | ((ycc - 1) & 7);
    const int laneYp = (lane & 56) | ((ycc + 1) & 7);

    const int xm = (x + 63) & 63;
    const int xp = (x + 1) & 63;
    // I2 source row: x-1 for x>0 (== xm), row 62 for x==0 (x==63's xm==62 too)

    const bool xedge = (x == 0) || (x == 63);
    const bool crn0  = xedge && (ycc == 0);    // y==0 is a grid corner
    const bool crn7  = xedge && (ycc == 7);    // y==63 is a grid corner

    float cxi[8], cex[8], xprev[8], wprev[8];
    #pragma unroll
    for (int j = 0; j < 8; ++j) {
        cxi[j] = 0.0f; cex[j] = 0.0f; xprev[j] = 0.0f; wprev[j] = 0.0f;
    }

    const float4 z4 = make_float4(0.0f, 0.0f, 0.0f, 0.0f);
    #pragma unroll
    for (int h = 0; h < 2; ++h) {
        *(float4*)&sxi[0][ldsOff(x, ycc, h)] = z4;
        *(float4*)&sex[0][ldsOff(x, ycc, h)] = z4;
    }
    __syncthreads();

    const float* Wb = W   + (size_t)b * 64 * 4096;
    float*       oB = out + (size_t)b * 64 * 4096 * 7;

    // prefetch W slice for t=0
    float wt[8];
    {
        const float* wp = Wb + x * 64 + yo;
        *(float4*)&wt[0] = *(const float4*)(wp);
        *(float4*)&wt[4] = *(const float4*)(wp + 4);
    }

    int cb = 0;
    for (int t = 0; t < 64; ++t) {
        // ---- prefetch W for t+1 (overlaps with LDS + store work) ----
        float wnext[8];
        if (t < 63) {
            const float* wp = Wb + (t + 1) * 4096 + x * 64 + yo;
            *(float4*)&wnext[0] = *(const float4*)(wp);
            *(float4*)&wnext[4] = *(const float4*)(wp + 4);
        }

        float dw[8];
        #pragma unroll
        for (int j = 0; j < 8; ++j)
            dw[j] = (t == 0) ? 0.0f : (wt[j] - wprev[j]) * IDT;
        #pragma unroll
        for (int j = 0; j < 8; ++j) wprev[j] = wt[j];

        // ---- xi-field x-neighbors (state t); xm row doubles as I2 source ----
        float nbm[8], nbp[8];
        *(float4*)&nbm[0] = *(const float4*)&sxi[cb][ldsOff(xm, ycc, 0)];
        *(float4*)&nbm[4] = *(const float4*)&sxi[cb][ldsOff(xm, ycc, 1)];
        *(float4*)&nbp[0] = *(const float4*)&sxi[cb][ldsOff(xp, ycc, 0)];
        *(float4*)&nbp[4] = *(const float4*)&sxi[cb][ldsOff(xp, ycc, 1)];

        float xi2[8];
        if (x == 0) {   // only wave 0's x==0 lanes take this masked extra read
            *(float4*)&xi2[0] = *(const float4*)&sxi[cb][ldsOff(62, ycc, 0)];
            *(float4*)&xi2[4] = *(const float4*)&sxi[cb][ldsOff(62, ycc, 1)];
        } else {
            #pragma unroll
            for (int j = 0; j < 8; ++j) xi2[j] = nbm[j];
        }

        // ---- store this block's channels at time t (owning waves only) ----
        if (mine) {
            float* base = oB + ((size_t)t * 4096 + x * 64 + yo) * 7;
            if (group == 0) {
                #pragma unroll
                for (int j = 0; j < 8; ++j) {
                    base[j * 7 + 0] = dw[j];
                    base[j * 7 + 1] = cxi[j];
                    base[j * 7 + 2] = (t == 0) ? 0.0f : -xprev[j];  // I1; t=0 fixed at t=63
                    base[j * 7 + 3] = -xi2[j];                      // I2
                }
            } else {
                const int ch = group + 3;   // 4,5,6
                #pragma unroll
                for (int j = 0; j < 8; ++j)
                    base[j * 7 + ch] = cex[j];
            }
        }

        if (t == 63) {
            // deferred: ch2 at t=0 is -I_xi[62] = -xprev (same thread overwrites)
            if (mine && group == 0) {
                float* p0 = oB + (size_t)(x * 64 + yo) * 7 + 2;
                #pragma unroll
                for (int j = 0; j < 8; ++j) p0[j * 7] = -xprev[j];
            }
        } else {
            const int nb = cb ^ 1;

            // ---- forcing for this block's extra field at time t ----
            float ge[8];
            if (group <= 1) {
                #pragma unroll
                for (int j = 0; j < 8; ++j) ge[j] = dw[j] * cxi[j];     // f4: dW * I_xi
            } else if (group == 2) {
                #pragma unroll
                for (int j = 0; j < 8; ++j) ge[j] = cxi[j] * cxi[j];    // f5: I_xi^2
            } else {
                #pragma unroll
                for (int j = 0; j < 8; ++j) ge[j] = xprev[j] * xi2[j];  // f6: I1*I2
            }
            #pragma unroll
            for (int j = 0; j < 8; ++j) xprev[j] = cxi[j];

            // ---- one explicit-Euler step per field ----
            auto stepCore = [&](float* c, const float* nm, const float* np_,
                                const float* g) {
                const float ym = __shfl(c[7], laneYm, 64);   // u[x, yo-1] (periodic)
                const float yp = __shfl(c[0], laneYp, 64);   // u[x, yo+8] (periodic)
                float n[8];
                #pragma unroll
                for (int j = 0; j < 8; ++j) {
                    const float left  = (j == 0) ? ym : c[j - 1];
                    const float right = (j == 7) ? yp : c[j + 1];
                    float lap = nm[j] + np_[j] + left + right - 4.0f * c[j];
                    if ((j == 0 && crn0) || (j == 7 && crn7)) lap = 0.0f; // corners
                    n[j] = c[j] + C2 * lap + g[j] * DTC;
                }
                #pragma unroll
                for (int j = 0; j < 8; ++j) c[j] = n[j];
            };

            // xi step: neighbors already loaded
            stepCore(cxi, nbm, nbp, dw);

            // extra-field step
            {
                float nm[8], np_[8];
                *(float4*)&nm[0]  = *(const float4*)&sex[cb][ldsOff(xm, ycc, 0)];
                *(float4*)&nm[4]  = *(const float4*)&sex[cb][ldsOff(xm, ycc, 1)];
                *(float4*)&np_[0] = *(const float4*)&sex[cb][ldsOff(xp, ycc, 0)];
                *(float4*)&np_[4] = *(const float4*)&sex[cb][ldsOff(xp, ycc, 1)];
                stepCore(cex, nm, np_, ge);
            }

            // write state t+1 into the other buffer; single barrier
            #pragma unroll
            for (int h = 0; h < 2; ++h) {
                *(float4*)&sxi[nb][ldsOff(x, ycc, h)] = *(float4*)&cxi[h << 2];
                *(float4*)&sex[nb][ldsOff(x, ycc, h)] = *(float4*)&cex[h << 2];
            }
            __syncthreads();
            cb = nb;

            #pragma unroll
            for (int j = 0; j < 8; ++j) wt[j] = wnext[j];
        }
    }
}

} // namespace

extern "C" void kernel_launch(void* const* d_in, const int* in_sizes, int n_in,
                              void* d_out, int out_size, void* d_ws, size_t ws_size,
                              hipStream_t stream) {
    const float* W  = (const float*)d_in[0];
    float* out      = (float*)d_out;
    hipLaunchKernelGGL(fused_scan, dim3(256), dim3(512), 0, stream, W, out);
}

// Round 3
// 349.176 us; speedup vs baseline: 1.1746x; 1.1746x over previous
//
#include <hip/hip_runtime.h>

namespace {

constexpr float C2  = 0.2f;   // DT/DX^2 (stencil coefficient)
constexpr float DTC = 0.2f;   // DT
constexpr float IDT = 5.0f;   // 1/DT

// LDS float offset for (row, ycc, h): float4-unit = (ycc + 8h) ^ (row&15).
__device__ __forceinline__ int ldsOff(int row, int ycc, int h) {
    return ((row << 4) + ((ycc + (h << 3)) ^ (row & 15))) << 2;   // float offset
}

// 256 blocks = 32 batches x 8 parts; every block runs the full 4-field scan
// (R0 structure -- R2's field-split regressed: scalar stores + no latency
// hiding). R3 change: BARRIER-FREE ring sync. R0's wall was the lockstep
// convoy: VALUBusy 45% + LDS-pipe ~45% that never overlap because all waves
// read LDS together, then all compute together. Wave w owns rows [8w,8w+8);
// its only LDS dependencies are waves w+-1 (rows 8w-1, 8w+8, and row 62 for
// the x==0 I2 path -> wave 7 = wave 0's wm1). Per-wave wdone/rdone flags in
// LDS (acquire/release) let adjacent waves skew +-1 timestep, overlapping
// one wave's VALU with another's LDS reads. Store duty also rotates across
// waves (ws = (part+t)&7 stores its rows at time t -- still an exact cover)
// so no single wave is the per-iteration straggler.
__global__ __launch_bounds__(512, 2)
void fused_scan(const float* __restrict__ W, float* __restrict__ out) {
    __shared__ float sxi[2][4096];
    __shared__ float s4 [2][4096];
    __shared__ float s5 [2][4096];
    __shared__ float s6 [2][4096];
    __shared__ int   wdone[8];   // latest state index wave has fully written
    __shared__ int   rdone[8];   // latest iteration whose reads completed

    const int tid  = threadIdx.x;
    // XCD-aligned mapping (R1 win: FETCH 131->16 MB): parts of one batch
    // differ by 32 in blockIdx -> same blockIdx%8 -> same XCD L2 image of W.
    const int b    = blockIdx.x & 31;
    const int part = blockIdx.x >> 5;        // 0..7

    const int x   = tid >> 3;      // row 0..63
    const int ycc = tid & 7;       // y-chunk 0..7 (8 consecutive y each)
    const int yo  = ycc << 3;      // first y of this thread
    const int wv  = tid >> 6;      // wave 0..7, owns rows [8wv, 8wv+8)
    const int wm1 = (wv + 7) & 7;
    const int wp1 = (wv + 1) & 7;

    // wave = 8 consecutive rows x 8 y-chunks; y+-1 neighbors are in-wave
    const int lane   = tid & 63;
    const int laneYm = (lane & 56) | ((ycc - 1) & 7);
    const int laneYp = (lane & 56) | ((ycc + 1) & 7);

    const int xm = (x + 63) & 63;
    const int xp = (x + 1) & 63;
    // I2 source row: x-1 for x>0 (== xm), row 62 for x==0 (x==63's xm==62 too)

    const bool xedge = (x == 0) || (x == 63);
    const bool crn0  = xedge && (ycc == 0);    // y==0 grid corner
    const bool crn7  = xedge && (ycc == 7);    // y==63 grid corner

    float cxi[8], c4[8], c5[8], c6[8], xprev[8], wprev[8];
    #pragma unroll
    for (int j = 0; j < 8; ++j) {
        cxi[j] = 0.0f; c4[j] = 0.0f; c5[j] = 0.0f; c6[j] = 0.0f;
        xprev[j] = 0.0f; wprev[j] = 0.0f;
    }

    if (tid < 8) {
        __hip_atomic_store(&wdone[tid], 0,  __ATOMIC_RELAXED, __HIP_MEMORY_SCOPE_WORKGROUP);
        __hip_atomic_store(&rdone[tid], -1, __ATOMIC_RELAXED, __HIP_MEMORY_SCOPE_WORKGROUP);
    }
    const float4 z4 = make_float4(0.0f, 0.0f, 0.0f, 0.0f);
    #pragma unroll
    for (int h = 0; h < 2; ++h) {
        *(float4*)&sxi[0][ldsOff(x, ycc, h)] = z4;
        *(float4*)&s4 [0][ldsOff(x, ycc, h)] = z4;
        *(float4*)&s5 [0][ldsOff(x, ycc, h)] = z4;
        *(float4*)&s6 [0][ldsOff(x, ycc, h)] = z4;
    }
    __syncthreads();   // the ONLY barrier: makes flag init + zero-fill safe

    // seed the wave skew so LDS bursts de-correlate immediately
    for (int i = 0; i < wv; ++i) __builtin_amdgcn_s_sleep(2);

    const float* Wb = W   + (size_t)b * 64 * 4096;
    float*       oB = out + (size_t)b * 64 * 4096 * 7;

    // prefetch W slice for t=0
    float wt[8];
    {
        const float* wp = Wb + x * 64 + yo;
        *(float4*)&wt[0] = *(const float4*)(wp);
        *(float4*)&wt[4] = *(const float4*)(wp + 4);
    }

    int cb = 0;
    for (int t = 0; t < 64; ++t) {
        // ---- prefetch W for t+1 (overlaps everything) ----
        float wnext[8];
        if (t < 63) {
            const float* wp = Wb + (t + 1) * 4096 + x * 64 + yo;
            *(float4*)&wnext[0] = *(const float4*)(wp);
            *(float4*)&wnext[4] = *(const float4*)(wp + 4);
        }

        // ---- dw (register-only, overlaps the flag wait) ----
        float dw[8];
        #pragma unroll
        for (int j = 0; j < 8; ++j)
            dw[j] = (t == 0) ? 0.0f : (wt[j] - wprev[j]) * IDT;
        #pragma unroll
        for (int j = 0; j < 8; ++j) wprev[j] = wt[j];

        // ---- wait: neighbor waves have written state t ----
        while (__hip_atomic_load(&wdone[wm1], __ATOMIC_ACQUIRE, __HIP_MEMORY_SCOPE_WORKGROUP) < t) {}
        while (__hip_atomic_load(&wdone[wp1], __ATOMIC_ACQUIRE, __HIP_MEMORY_SCOPE_WORKGROUP) < t) {}

        // ---- neighbor reads for all 4 fields (front-loaded) ----
        float nbm[8], nbp[8];
        *(float4*)&nbm[0] = *(const float4*)&sxi[cb][ldsOff(xm, ycc, 0)];
        *(float4*)&nbm[4] = *(const float4*)&sxi[cb][ldsOff(xm, ycc, 1)];
        *(float4*)&nbp[0] = *(const float4*)&sxi[cb][ldsOff(xp, ycc, 0)];
        *(float4*)&nbp[4] = *(const float4*)&sxi[cb][ldsOff(xp, ycc, 1)];

        float xi2[8];
        if (x == 0) {   // wave 0's x==0 lanes read row 62 (owned by wave 7 = wm1)
            *(float4*)&xi2[0] = *(const float4*)&sxi[cb][ldsOff(62, ycc, 0)];
            *(float4*)&xi2[4] = *(const float4*)&sxi[cb][ldsOff(62, ycc, 1)];
        } else {
            #pragma unroll
            for (int j = 0; j < 8; ++j) xi2[j] = nbm[j];
        }

        float nm4[8], np4[8], nm5[8], np5[8], nm6[8], np6[8];
        *(float4*)&nm4[0] = *(const float4*)&s4[cb][ldsOff(xm, ycc, 0)];
        *(float4*)&nm4[4] = *(const float4*)&s4[cb][ldsOff(xm, ycc, 1)];
        *(float4*)&np4[0] = *(const float4*)&s4[cb][ldsOff(xp, ycc, 0)];
        *(float4*)&np4[4] = *(const float4*)&s4[cb][ldsOff(xp, ycc, 1)];
        *(float4*)&nm5[0] = *(const float4*)&s5[cb][ldsOff(xm, ycc, 0)];
        *(float4*)&nm5[4] = *(const float4*)&s5[cb][ldsOff(xm, ycc, 1)];
        *(float4*)&np5[0] = *(const float4*)&s5[cb][ldsOff(xp, ycc, 0)];
        *(float4*)&np5[4] = *(const float4*)&s5[cb][ldsOff(xp, ycc, 1)];
        *(float4*)&nm6[0] = *(const float4*)&s6[cb][ldsOff(xm, ycc, 0)];
        *(float4*)&nm6[4] = *(const float4*)&s6[cb][ldsOff(xm, ycc, 1)];
        *(float4*)&np6[0] = *(const float4*)&s6[cb][ldsOff(xp, ycc, 0)];
        *(float4*)&np6[4] = *(const float4*)&s6[cb][ldsOff(xp, ycc, 1)];

        // ---- mark reads complete (drain lgkm, then relaxed flag) ----
        asm volatile("s_waitcnt lgkmcnt(0)" ::: "memory");
        __hip_atomic_store(&rdone[wv], t, __ATOMIC_RELAXED, __HIP_MEMORY_SCOPE_WORKGROUP);

        // ---- store the 7 channels at time t (rotating owner wave) ----
        if (wv == ((part + t) & 7)) {
            #pragma unroll
            for (int h = 0; h < 2; ++h) {
                float4 ov[7];
                float* o = (float*)ov;
                #pragma unroll
                for (int j = 0; j < 4; ++j) {
                    const int jj = (h << 2) + j;
                    o[j * 7 + 0] = dw[jj];
                    o[j * 7 + 1] = cxi[jj];
                    o[j * 7 + 2] = (t == 0) ? 0.0f : -xprev[jj];  // I1; t=0 fixed post-loop
                    o[j * 7 + 3] = -xi2[jj];                      // I2
                    o[j * 7 + 4] = c4[jj];
                    o[j * 7 + 5] = c5[jj];
                    o[j * 7 + 6] = c6[jj];
                }
                float4* dst = (float4*)(oB + ((size_t)t * 4096 + x * 64 + yo + (h << 2)) * 7);
                #pragma unroll
                for (int k = 0; k < 7; ++k) dst[k] = ov[k];
            }
        }

        if (t < 63) {
            // ---- forcings at time t ----
            float g4v[8], g5v[8], g6v[8];
            #pragma unroll
            for (int j = 0; j < 8; ++j) {
                g4v[j] = dw[j] * cxi[j];          // dW * I_xi
                g5v[j] = cxi[j] * cxi[j];         // I_xi^2
                g6v[j] = xprev[j] * xi2[j];       // (-I_xi[t-1]) * (-shift(I_xi[t]))
            }
            #pragma unroll
            for (int j = 0; j < 8; ++j) xprev[j] = cxi[j];

            // ---- one explicit-Euler step per field (register-only) ----
            auto stepCore = [&](float* c, const float* nm, const float* np_,
                                const float* g) {
                const float ym = __shfl(c[7], laneYm, 64);   // u[x, yo-1] (periodic)
                const float yp = __shfl(c[0], laneYp, 64);   // u[x, yo+8] (periodic)
                float n[8];
                #pragma unroll
                for (int j = 0; j < 8; ++j) {
                    const float left  = (j == 0) ? ym : c[j - 1];
                    const float right = (j == 7) ? yp : c[j + 1];
                    float lap = nm[j] + np_[j] + left + right - 4.0f * c[j];
                    if ((j == 0 && crn0) || (j == 7 && crn7)) lap = 0.0f; // corners
                    n[j] = c[j] + C2 * lap + g[j] * DTC;
                }
                #pragma unroll
                for (int j = 0; j < 8; ++j) c[j] = n[j];
            };

            stepCore(cxi, nbm, nbp, dw);
            stepCore(c4,  nm4, np4, g4v);
            stepCore(c5,  nm5, np5, g5v);
            stepCore(c6,  nm6, np6, g6v);

            // ---- wait: neighbors consumed state t-1 from the buffer we
            //      are about to overwrite (they read our boundary rows) ----
            while (__hip_atomic_load(&rdone[wm1], __ATOMIC_ACQUIRE, __HIP_MEMORY_SCOPE_WORKGROUP) < t - 1) {}
            while (__hip_atomic_load(&rdone[wp1], __ATOMIC_ACQUIRE, __HIP_MEMORY_SCOPE_WORKGROUP) < t - 1) {}

            const int nb = cb ^ 1;
            #pragma unroll
            for (int h = 0; h < 2; ++h) {
                *(float4*)&sxi[nb][ldsOff(x, ycc, h)] = *(float4*)&cxi[h << 2];
                *(float4*)&s4 [nb][ldsOff(x, ycc, h)] = *(float4*)&c4 [h << 2];
                *(float4*)&s5 [nb][ldsOff(x, ycc, h)] = *(float4*)&c5 [h << 2];
                *(float4*)&s6 [nb][ldsOff(x, ycc, h)] = *(float4*)&c6 [h << 2];
            }
            // publish state t+1 (drain lgkm, then relaxed flag)
            asm volatile("s_waitcnt lgkmcnt(0)" ::: "memory");
            __hip_atomic_store(&wdone[wv], t + 1, __ATOMIC_RELAXED, __HIP_MEMORY_SCOPE_WORKGROUP);
            cb = nb;

            #pragma unroll
            for (int j = 0; j < 8; ++j) wt[j] = wnext[j];
        }
    }

    // deferred: ch2 at t=0 is -I_xi[62] = -xprev (wave `part` stored t=0 rows)
    if (wv == part) {
        float* p0 = oB + (size_t)(x * 64 + yo) * 7 + 2;
        #pragma unroll
        for (int j = 0; j < 8; ++j) p0[j * 7] = -xprev[j];
    }
}

} // namespace

extern "C" void kernel_launch(void* const* d_in, const int* in_sizes, int n_in,
                              void* d_out, int out_size, void* d_ws, size_t ws_size,
                              hipStream_t stream) {
    const float* W  = (const float*)d_in[0];
    float* out      = (float*)d_out;
    hipLaunchKernelGGL(fused_scan, dim3(256), dim3(512), 0, stream, W, out);
}